// Round 3
// baseline (1202.507 us; speedup 1.0000x reference)
//
#include <hip/hip_runtime.h>
#include <math.h>

#define NN 50000
#define NE 600000
#define DIM 128
#define NL 12
#define BM 64

typedef short bf16x8 __attribute__((ext_vector_type(8)));
typedef float f32x4 __attribute__((ext_vector_type(4)));

__device__ __forceinline__ uint f2b_rne(float f) {
    uint u = __float_as_uint(f);
    return (u + 0x7fffu + ((u >> 16) & 1u)) >> 16;
}

// ---------------- fp32 -> bf16 convert (8 elems/thread) ----------------
__global__ void cvt_kernel(const float* __restrict__ in, ushort* __restrict__ out, int n8) {
    int i = blockIdx.x * blockDim.x + threadIdx.x;
    if (i >= n8) return;
    const float4* p = reinterpret_cast<const float4*>(in);
    float4 v0 = p[i * 2], v1 = p[i * 2 + 1];
    uint4 o;
    o.x = (f2b_rne(v0.y) << 16) | f2b_rne(v0.x);
    o.y = (f2b_rne(v0.w) << 16) | f2b_rne(v0.z);
    o.z = (f2b_rne(v1.y) << 16) | f2b_rne(v1.x);
    o.w = (f2b_rne(v1.w) << 16) | f2b_rne(v1.z);
    reinterpret_cast<uint4*>(out)[i] = o;
}

// ---------------- CSR build ----------------
__global__ void count_kernel(const int* __restrict__ dst, int* __restrict__ counts) {
    int e = blockIdx.x * blockDim.x + threadIdx.x;
    if (e < NE) atomicAdd(&counts[dst[e]], 1);
}

__global__ __launch_bounds__(1024) void scan1_kernel(const int* __restrict__ counts,
                                                     int* __restrict__ offsets,
                                                     int* __restrict__ bsums) {
    int b = blockIdx.x, t = threadIdx.x;
    int i = b * 1024 + t;
    int lane = t & 63, wid = t >> 6;
    int val = (i < NN) ? counts[i] : 0;
#pragma unroll
    for (int o = 1; o < 64; o <<= 1) {
        int n = __shfl_up(val, o);
        if (lane >= o) val += n;
    }
    __shared__ int ws[16];
    if (lane == 63) ws[wid] = val;
    __syncthreads();
    if (wid == 0 && lane < 16) {
        int s = ws[lane];
#pragma unroll
        for (int o = 1; o < 16; o <<= 1) {
            int n = __shfl_up(s, o);
            if (lane >= o) s += n;
        }
        ws[lane] = s;
    }
    __syncthreads();
    if (wid) val += ws[wid - 1];
    if (i < NN) offsets[i + 1] = val;
    if (t == 1023) bsums[b] = val;
}

__global__ void scan2_kernel(const int* __restrict__ bsums, int* __restrict__ bbase, int nb) {
    int lane = threadIdx.x;
    int v = (lane < nb) ? bsums[lane] : 0;
    int val = v;
#pragma unroll
    for (int o = 1; o < 64; o <<= 1) {
        int n = __shfl_up(val, o);
        if (lane >= o) val += n;
    }
    if (lane < nb) bbase[lane] = val - v;   // exclusive
}

__global__ void scan3_kernel(int* __restrict__ offsets, const int* __restrict__ bbase) {
    int i = blockIdx.x * blockDim.x + threadIdx.x;
    if (i == 0) { offsets[0] = 0; return; }
    if (i <= NN) offsets[i] += bbase[(i - 1) >> 10];
}

__global__ void fill_kernel(const int* __restrict__ src, const int* __restrict__ dst,
                            const int* __restrict__ offsets, int* __restrict__ cursor,
                            int* __restrict__ csr) {
    int e = blockIdx.x * blockDim.x + threadIdx.x;
    if (e < NE) {
        int d = dst[e];
        int p = atomicAdd(&cursor[d], 1);
        csr[offsets[d] + p] = src[e];
    }
}

// ---------------- fused layer: aggregate(16 nodes/wave -> LDS) + dual MFMA GEMM ----------------
// AGGR: 0=sum, 1=mean, 2=max, 3 = no-aggregate single-pass (final MLP layer)
// C[n][:] = relu( agg[n] @ Wa^T + h[n] @ Wb^T + bias )     (AGGR<3)
// C[n][:] = relu( h[n] @ Wa^T + bias )                     (AGGR==3)
// MFMA operands SWAPPED: mfma(W-frag as A, node-frag as B) -> D[m=outcol][n=noderow],
// so each lane holds 4 consecutive out cols -> packed uint2 stores.
template <int AGGR>
__global__ __launch_bounds__(256, 4) void layer_kernel(
    const ushort* __restrict__ h, const ushort* __restrict__ Wa,
    const ushort* __restrict__ Wb, const float* __restrict__ bias,
    ushort* __restrict__ C,
    const int* __restrict__ csr, const int* __restrict__ offsets) {
    __shared__ char lds[BM * 256];     // [64 rows][128 bf16], XOR-swizzled chunks
    int t = threadIdx.x, w = t >> 6, l = t & 63;
    int lr = l & 15, lg = l >> 4;
    int row0 = blockIdx.x * BM;
    const uint* hp = reinterpret_cast<const uint*>(h);

    if (AGGR != 3) {
        // ---- phase 1: each wave aggregates 16 nodes, lane covers 2 cols ----
        for (int i = 0; i < 16; ++i) {
            int lrow = w * 16 + i;
            int row = row0 + lrow;
            float ax = (AGGR == 2) ? -INFINITY : 0.f;
            float ay = ax;
            if (row < NN) {
                int s0 = offsets[row], s1 = offsets[row + 1];
                int e = s0;
                for (; e + 7 < s1; e += 8) {
                    uint u[8];
#pragma unroll
                    for (int q = 0; q < 8; ++q) u[q] = hp[(size_t)csr[e + q] * 64 + l];
#pragma unroll
                    for (int q = 0; q < 8; ++q) {
                        float fx = __uint_as_float(u[q] << 16);
                        float fy = __uint_as_float(u[q] & 0xffff0000u);
                        if (AGGR == 2) { ax = fmaxf(ax, fx); ay = fmaxf(ay, fy); }
                        else           { ax += fx;           ay += fy; }
                    }
                }
                for (; e < s1; ++e) {
                    uint u = hp[(size_t)csr[e] * 64 + l];
                    float fx = __uint_as_float(u << 16);
                    float fy = __uint_as_float(u & 0xffff0000u);
                    if (AGGR == 2) { ax = fmaxf(ax, fx); ay = fmaxf(ay, fy); }
                    else           { ax += fx;           ay += fy; }
                }
                int deg = s1 - s0;
                if (AGGR == 1) { float inv = 1.f / (float)(deg > 0 ? deg : 1); ax *= inv; ay *= inv; }
                if (AGGR == 2 && deg == 0) { ax = 0.f; ay = 0.f; }
            }
            uint o = (f2b_rne(ay) << 16) | f2b_rne(ax);
            *reinterpret_cast<uint*>(lds + lrow * 256 + ((l * 4) ^ ((lrow & 7) << 4))) = o;
        }
        __syncthreads();
    }

    // ---- phase 2: MFMA. wave w owns node rows row0 + w*16 .. +15 ----
    f32x4 acc[8];
#pragma unroll
    for (int c = 0; c < 8; ++c) acc[c] = (f32x4){0.f, 0.f, 0.f, 0.f};
    int lrow = w * 16 + lr;
    int grow = min(row0 + lrow, NN - 1);

    const int NPASS = (AGGR == 3) ? 1 : 2;
#pragma unroll
    for (int pass = 0; pass < NPASS; ++pass) {
        const ushort* W = pass ? Wb : Wa;
#pragma unroll
        for (int kk = 0; kk < 4; ++kk) {
            bf16x8 bfrag;
            if (AGGR != 3 && pass == 0)
                bfrag = *reinterpret_cast<const bf16x8*>(
                    lds + lrow * 256 + ((kk * 64 + lg * 16) ^ ((lrow & 7) << 4)));
            else
                bfrag = *reinterpret_cast<const bf16x8*>(h + (size_t)grow * DIM + kk * 32 + lg * 8);
#pragma unroll
            for (int c = 0; c < 8; ++c) {
                bf16x8 wf = *reinterpret_cast<const bf16x8*>(
                    W + (size_t)(c * 16 + lr) * DIM + kk * 32 + lg * 8);
                acc[c] = __builtin_amdgcn_mfma_f32_16x16x32_bf16(wf, bfrag, acc[c], 0, 0, 0);
            }
        }
    }

    // ---- epilogue: D[m][n]: out col = c*16 + lg*4 + i, node row = row0 + w*16 + lr ----
    int orow = row0 + w * 16 + lr;
    if (orow < NN) {
#pragma unroll
        for (int c = 0; c < 8; ++c) {
            int col0 = c * 16 + lg * 4;
            float4 b4 = *reinterpret_cast<const float4*>(bias + col0);
            float v0 = fmaxf(acc[c][0] + b4.x, 0.f);
            float v1 = fmaxf(acc[c][1] + b4.y, 0.f);
            float v2 = fmaxf(acc[c][2] + b4.z, 0.f);
            float v3 = fmaxf(acc[c][3] + b4.w, 0.f);
            uint2 o;
            o.x = (f2b_rne(v1) << 16) | f2b_rne(v0);
            o.y = (f2b_rne(v3) << 16) | f2b_rne(v2);
            *reinterpret_cast<uint2*>(C + (size_t)orow * DIM + col0) = o;
        }
    }
}

// ---------------- final 128 -> 2 projection ----------------
__global__ void out_kernel(const ushort* __restrict__ h2, const float* __restrict__ W2,
                           const float* __restrict__ b2, float* __restrict__ out) {
    int wid = (blockIdx.x * blockDim.x + threadIdx.x) >> 6;
    int lane = threadIdx.x & 63;
    if (wid >= NN) return;
    uint u = reinterpret_cast<const uint*>(h2)[(size_t)wid * 64 + lane];
    float vx = __uint_as_float(u << 16), vy = __uint_as_float(u & 0xffff0000u);
    float2 w0 = *reinterpret_cast<const float2*>(W2 + lane * 2);
    float2 w1 = *reinterpret_cast<const float2*>(W2 + DIM + lane * 2);
    float s0 = vx * w0.x + vy * w0.y;
    float s1 = vx * w1.x + vy * w1.y;
    for (int off = 32; off; off >>= 1) {
        s0 += __shfl_down(s0, off);
        s1 += __shfl_down(s1, off);
    }
    if (lane == 0) {
        out[wid * 2 + 0] = s0 + b2[0];
        out[wid * 2 + 1] = s1 + b2[1];
    }
}

extern "C" void kernel_launch(void* const* d_in, const int* in_sizes, int n_in,
                              void* d_out, int out_size, void* d_ws, size_t ws_size,
                              hipStream_t stream) {
    const float* x  = (const float*)d_in[0];
    const int*   ei = (const int*)d_in[1];
    const float* Wl = (const float*)d_in[2];
    const float* bl = (const float*)d_in[3];
    const float* Wr = (const float*)d_in[4];
    const float* W1 = (const float*)d_in[5];
    const float* b1 = (const float*)d_in[6];
    const float* W2 = (const float*)d_in[7];
    const float* b2 = (const float*)d_in[8];
    float* out = (float*)d_out;

    // ---- workspace layout ----
    int* counts  = (int*)d_ws;                      // NN
    int* offsets = counts + NN;                     // NN+1
    int* bsums   = offsets + NN + 1;                // 64
    int* bbase   = bsums + 64;                      // 64
    int* csr     = bbase + 64;                      // NE
    size_t fixed = ((size_t)(NN + NN + 1 + 128 + NE) * sizeof(int) + 255) & ~(size_t)255;
    ushort* xb   = (ushort*)((char*)d_ws + fixed);  // NN*DIM bf16
    ushort* bufA = xb + (size_t)NN * DIM;
    ushort* bufB = bufA + (size_t)NN * DIM;
    ushort* Wlb  = bufB + (size_t)NN * DIM;         // 12*128*128
    ushort* Wrb  = Wlb + (size_t)NL * DIM * DIM;
    ushort* W1b  = Wrb + (size_t)NL * DIM * DIM;    // 128*128

    const int* src = ei;
    const int* dst = ei + NE;

    cvt_kernel<<<(NN * DIM / 8 + 255) / 256, 256, 0, stream>>>(x, xb, NN * DIM / 8);
    cvt_kernel<<<(NL * DIM * DIM / 8 + 255) / 256, 256, 0, stream>>>(Wl, Wlb, NL * DIM * DIM / 8);
    cvt_kernel<<<(NL * DIM * DIM / 8 + 255) / 256, 256, 0, stream>>>(Wr, Wrb, NL * DIM * DIM / 8);
    cvt_kernel<<<(DIM * DIM / 8 + 255) / 256, 256, 0, stream>>>(W1, W1b, DIM * DIM / 8);

    const int NB = (NN + 1023) / 1024;   // 49
    hipMemsetAsync(counts, 0, NN * sizeof(int), stream);
    count_kernel<<<(NE + 255) / 256, 256, 0, stream>>>(dst, counts);
    scan1_kernel<<<NB, 1024, 0, stream>>>(counts, offsets, bsums);
    scan2_kernel<<<1, 64, 0, stream>>>(bsums, bbase, NB);
    scan3_kernel<<<(NN + 1 + 255) / 256, 256, 0, stream>>>(offsets, bbase);
    hipMemsetAsync(counts, 0, NN * sizeof(int), stream);
    fill_kernel<<<(NE + 255) / 256, 256, 0, stream>>>(src, dst, offsets, counts, csr);

    static const int AGGRS[NL] = {0, 1, 2, 0, 1, 2, 0, 1, 2, 0, 2, 1};
    const ushort* h = xb;
    dim3 lgrd((NN + BM - 1) / BM);       // 782
    dim3 agrd((NN * 64 + 255) / 256);    // for out_kernel
    for (int i = 0; i < NL; ++i) {
        ushort* obuf = (i & 1) ? bufB : bufA;
        const ushort* wa = Wlb + (size_t)i * DIM * DIM;
        const ushort* wb = Wrb + (size_t)i * DIM * DIM;
        const float* bi = bl + (size_t)i * DIM;
        if (AGGRS[i] == 0)
            layer_kernel<0><<<lgrd, 256, 0, stream>>>(h, wa, wb, bi, obuf, csr, offsets);
        else if (AGGRS[i] == 1)
            layer_kernel<1><<<lgrd, 256, 0, stream>>>(h, wa, wb, bi, obuf, csr, offsets);
        else
            layer_kernel<2><<<lgrd, 256, 0, stream>>>(h, wa, wb, bi, obuf, csr, offsets);
        h = obuf;
    }
    // final MLP: relu(h@W1^T + b1) -> xb (free after layer 0), then 128->2 projection
    layer_kernel<3><<<lgrd, 256, 0, stream>>>(h, W1b, nullptr, b1, xb, csr, offsets);
    out_kernel<<<agrd, 256, 0, stream>>>(xb, W2, b2, out);
}

// Round 5
// 1002.122 us; speedup vs baseline: 1.2000x; 1.2000x over previous
//
#include <hip/hip_runtime.h>
#include <math.h>

#define NN 50000
#define NE 600000
#define DIM 128
#define NL 12

typedef short bf16x8 __attribute__((ext_vector_type(8)));
typedef float f32x4 __attribute__((ext_vector_type(4)));

__device__ __forceinline__ uint f2b_rne(float f) {
    uint u = __float_as_uint(f);
    return (u + 0x7fffu + ((u >> 16) & 1u)) >> 16;
}

// ---------------- fused fp32 -> bf16 convert for all 4 tensors ----------------
#define NX8 (NN * DIM / 8)               // 800000
#define NW8 (NL * DIM * DIM / 8)         // 24576
#define NW18 (DIM * DIM / 8)             // 2048
__global__ void cvt_all(const float* __restrict__ x, const float* __restrict__ Wl,
                        const float* __restrict__ Wr, const float* __restrict__ W1,
                        ushort* __restrict__ xb, ushort* __restrict__ Wlb,
                        ushort* __restrict__ Wrb, ushort* __restrict__ W1b) {
    int i = blockIdx.x * blockDim.x + threadIdx.x;
    const float* in; ushort* out; int off;
    if (i < NX8)                        { in = x;  out = xb;  off = i; }
    else if (i < NX8 + NW8)             { in = Wl; out = Wlb; off = i - NX8; }
    else if (i < NX8 + 2 * NW8)         { in = Wr; out = Wrb; off = i - NX8 - NW8; }
    else if (i < NX8 + 2 * NW8 + NW18)  { in = W1; out = W1b; off = i - NX8 - 2 * NW8; }
    else return;
    const float4* p = reinterpret_cast<const float4*>(in);
    float4 v0 = p[off * 2], v1 = p[off * 2 + 1];
    uint4 o;
    o.x = (f2b_rne(v0.y) << 16) | f2b_rne(v0.x);
    o.y = (f2b_rne(v0.w) << 16) | f2b_rne(v0.z);
    o.z = (f2b_rne(v1.y) << 16) | f2b_rne(v1.x);
    o.w = (f2b_rne(v1.w) << 16) | f2b_rne(v1.z);
    reinterpret_cast<uint4*>(out)[off] = o;
}

// ---------------- CSR build ----------------
__global__ void count_kernel(const int* __restrict__ dst, int* __restrict__ counts) {
    int e = blockIdx.x * blockDim.x + threadIdx.x;
    if (e < NE) atomicAdd(&counts[dst[e]], 1);
}

__global__ __launch_bounds__(1024) void scan1_kernel(const int* __restrict__ counts,
                                                     int* __restrict__ offsets,
                                                     int* __restrict__ bsums) {
    int b = blockIdx.x, t = threadIdx.x;
    int i = b * 1024 + t;
    int lane = t & 63, wid = t >> 6;
    int val = (i < NN) ? counts[i] : 0;
#pragma unroll
    for (int o = 1; o < 64; o <<= 1) {
        int n = __shfl_up(val, o);
        if (lane >= o) val += n;
    }
    __shared__ int ws[16];
    if (lane == 63) ws[wid] = val;
    __syncthreads();
    if (wid == 0 && lane < 16) {
        int s = ws[lane];
#pragma unroll
        for (int o = 1; o < 16; o <<= 1) {
            int n = __shfl_up(s, o);
            if (lane >= o) s += n;
        }
        ws[lane] = s;
    }
    __syncthreads();
    if (wid) val += ws[wid - 1];
    if (i < NN) offsets[i + 1] = val;
    if (t == 1023) bsums[b] = val;
}

__global__ void scan2_kernel(const int* __restrict__ bsums, int* __restrict__ bbase, int nb) {
    int lane = threadIdx.x;
    int v = (lane < nb) ? bsums[lane] : 0;
    int val = v;
#pragma unroll
    for (int o = 1; o < 64; o <<= 1) {
        int n = __shfl_up(val, o);
        if (lane >= o) val += n;
    }
    if (lane < nb) bbase[lane] = val - v;   // exclusive
}

__global__ void scan3_kernel(int* __restrict__ offsets, const int* __restrict__ bbase) {
    int i = blockIdx.x * blockDim.x + threadIdx.x;
    if (i == 0) { offsets[0] = 0; return; }
    if (i <= NN) offsets[i] += bbase[(i - 1) >> 10];
}

__global__ void fill_kernel(const int* __restrict__ src, const int* __restrict__ dst,
                            const int* __restrict__ offsets, int* __restrict__ cursor,
                            int* __restrict__ csr) {
    int e = blockIdx.x * blockDim.x + threadIdx.x;
    if (e < NE) {
        int d = dst[e];
        int p = atomicAdd(&cursor[d], 1);
        csr[offsets[d] + p] = src[e];
    }
}

// ---------------- aggregation: one wave per node, 2 edges wide, 8-deep unroll ----------------
// Lanes 0-31 handle even-slot edges, 32-63 odd-slot; each lane covers 4 cols (uint2).
// 16 edges in flight per wave; fully predicated (no serial tail).
// AGGR: 0=sum, 1=mean, 2=max
template <int AGGR>
__global__ __launch_bounds__(256) void aggregate_kernel(
    const ushort* __restrict__ h, ushort* __restrict__ agg,
    const int* __restrict__ csr, const int* __restrict__ offsets) {
    int wid = (blockIdx.x * blockDim.x + threadIdx.x) >> 6;
    int l = threadIdx.x & 63;
    if (wid >= NN) return;
    int half = l >> 5, li = l & 31;
    int s0 = offsets[wid], s1 = offsets[wid + 1];
    const uint2* hp = reinterpret_cast<const uint2*>(h);   // row = 32 uint2
    float a0, a1, a2, a3;
    if (AGGR == 2) { a0 = a1 = a2 = a3 = -INFINITY; } else { a0 = a1 = a2 = a3 = 0.f; }
    for (int e = s0 + half; e < s1; e += 16) {
        uint2 u[8];
        int ok[8];
#pragma unroll
        for (int q = 0; q < 8; ++q) {
            int ee = e + q * 2;
            ok[q] = ee < s1;
            int idx = ok[q] ? csr[ee] : 0;       // masked slots read row 0 (L1-hit broadcast)
            u[q] = hp[(size_t)idx * 32 + li];
        }
#pragma unroll
        for (int q = 0; q < 8; ++q) {
            float x0 = __uint_as_float(u[q].x << 16);
            float y0 = __uint_as_float(u[q].x & 0xffff0000u);
            float x1 = __uint_as_float(u[q].y << 16);
            float y1 = __uint_as_float(u[q].y & 0xffff0000u);
            if (AGGR == 2) {
                if (ok[q]) {
                    a0 = fmaxf(a0, x0); a1 = fmaxf(a1, y0);
                    a2 = fmaxf(a2, x1); a3 = fmaxf(a3, y1);
                }
            } else {
                if (ok[q]) { a0 += x0; a1 += y0; a2 += x1; a3 += y1; }
            }
        }
    }
    // combine the two edge-halves (same cols in both halves)
    float b0 = __shfl_xor(a0, 32), b1 = __shfl_xor(a1, 32);
    float b2 = __shfl_xor(a2, 32), b3 = __shfl_xor(a3, 32);
    if (AGGR == 2) { a0 = fmaxf(a0, b0); a1 = fmaxf(a1, b1); a2 = fmaxf(a2, b2); a3 = fmaxf(a3, b3); }
    else           { a0 += b0; a1 += b1; a2 += b2; a3 += b3; }
    int deg = s1 - s0;
    if (AGGR == 1) {
        float inv = 1.f / (float)(deg > 0 ? deg : 1);
        a0 *= inv; a1 *= inv; a2 *= inv; a3 *= inv;
    }
    if (AGGR == 2 && deg == 0) { a0 = a1 = a2 = a3 = 0.f; }
    if (half == 0) {
        uint2 o;
        o.x = (f2b_rne(a1) << 16) | f2b_rne(a0);
        o.y = (f2b_rne(a3) << 16) | f2b_rne(a2);
        reinterpret_cast<uint2*>(agg)[(size_t)wid * 32 + li] = o;
    }
}

// ---------------- MFMA GEMM, no LDS, swapped operands ----------------
// C[n][:] = relu(A1[n] @ Wa^T [+ A2[n] @ Wb^T] + bias)
// Block = 4 waves x 16 rows = 64 rows; wave w owns rows blockIdx.x*64 + w*16 + (0..15).
// mfma(W-frag as A, node-frag as B) -> D[m=outcol][n=node]:
//   A-frag: lane holds W[c*16 + (l&15)][(l>>4)*8 ..+7]  (out-col = l&15 within tile)
//   B-frag: lane holds A[row0 + (l&15)][(l>>4)*8 ..+7]  (node    = l&15 within tile)
//   D:      node col = l&15, out-col row = (l>>4)*4 + reg  -> packed uint2 stores
template <int NPASS>
__global__ __launch_bounds__(256) void gemm_kernel(
    const ushort* __restrict__ A1, const ushort* __restrict__ Wa,
    const ushort* __restrict__ A2, const ushort* __restrict__ Wb,
    const float* __restrict__ bias, ushort* __restrict__ C) {
    int t = threadIdx.x, w = t >> 6, l = t & 63;
    int lr = l & 15, lg = l >> 4;
    int row0 = blockIdx.x * 64 + w * 16;     // wave offset folded in ONCE
    f32x4 acc[8];
#pragma unroll
    for (int c = 0; c < 8; ++c) acc[c] = (f32x4){0.f, 0.f, 0.f, 0.f};
    int grow = min(row0 + lr, NN - 1);   // clamp; OOB rows discarded at store

#pragma unroll
    for (int pass = 0; pass < NPASS; ++pass) {
        const ushort* A = pass ? A2 : A1;
        const ushort* W = pass ? Wb : Wa;
#pragma unroll
        for (int kk = 0; kk < 4; ++kk) {
            bf16x8 nfrag = *reinterpret_cast<const bf16x8*>(A + (size_t)grow * DIM + kk * 32 + lg * 8);
#pragma unroll
            for (int c = 0; c < 8; ++c) {
                bf16x8 wf = *reinterpret_cast<const bf16x8*>(
                    W + (size_t)(c * 16 + lr) * DIM + kk * 32 + lg * 8);
                acc[c] = __builtin_amdgcn_mfma_f32_16x16x32_bf16(wf, nfrag, acc[c], 0, 0, 0);
            }
        }
    }
    int orow = row0 + lr;                // node row == B-fragment node (grow before clamp)
    if (orow < NN) {
#pragma unroll
        for (int c = 0; c < 8; ++c) {
            int col0 = c * 16 + lg * 4;
            float4 b4 = *reinterpret_cast<const float4*>(bias + col0);
            float v0 = fmaxf(acc[c][0] + b4.x, 0.f);
            float v1 = fmaxf(acc[c][1] + b4.y, 0.f);
            float v2 = fmaxf(acc[c][2] + b4.z, 0.f);
            float v3 = fmaxf(acc[c][3] + b4.w, 0.f);
            uint2 o;
            o.x = (f2b_rne(v1) << 16) | f2b_rne(v0);
            o.y = (f2b_rne(v3) << 16) | f2b_rne(v2);
            *reinterpret_cast<uint2*>(C + (size_t)orow * DIM + col0) = o;
        }
    }
}

// ---------------- final 128 -> 2 projection ----------------
__global__ void out_kernel(const ushort* __restrict__ h2, const float* __restrict__ W2,
                           const float* __restrict__ b2, float* __restrict__ out) {
    int wid = (blockIdx.x * blockDim.x + threadIdx.x) >> 6;
    int lane = threadIdx.x & 63;
    if (wid >= NN) return;
    uint u = reinterpret_cast<const uint*>(h2)[(size_t)wid * 64 + lane];
    float vx = __uint_as_float(u << 16), vy = __uint_as_float(u & 0xffff0000u);
    float2 w0 = *reinterpret_cast<const float2*>(W2 + lane * 2);
    float2 w1 = *reinterpret_cast<const float2*>(W2 + DIM + lane * 2);
    float s0 = vx * w0.x + vy * w0.y;
    float s1 = vx * w1.x + vy * w1.y;
    for (int off = 32; off; off >>= 1) {
        s0 += __shfl_down(s0, off);
        s1 += __shfl_down(s1, off);
    }
    if (lane == 0) {
        out[wid * 2 + 0] = s0 + b2[0];
        out[wid * 2 + 1] = s1 + b2[1];
    }
}

extern "C" void kernel_launch(void* const* d_in, const int* in_sizes, int n_in,
                              void* d_out, int out_size, void* d_ws, size_t ws_size,
                              hipStream_t stream) {
    const float* x  = (const float*)d_in[0];
    const int*   ei = (const int*)d_in[1];
    const float* Wl = (const float*)d_in[2];
    const float* bl = (const float*)d_in[3];
    const float* Wr = (const float*)d_in[4];
    const float* W1 = (const float*)d_in[5];
    const float* b1 = (const float*)d_in[6];
    const float* W2 = (const float*)d_in[7];
    const float* b2 = (const float*)d_in[8];
    float* out = (float*)d_out;

    // ---- workspace layout ----
    int* counts  = (int*)d_ws;                      // NN
    int* offsets = counts + NN;                     // NN+1
    int* bsums   = offsets + NN + 1;                // 64
    int* bbase   = bsums + 64;                      // 64
    int* csr     = bbase + 64;                      // NE
    size_t fixed = ((size_t)(NN + NN + 1 + 128 + NE) * sizeof(int) + 255) & ~(size_t)255;
    ushort* xb   = (ushort*)((char*)d_ws + fixed);  // NN*DIM bf16
    ushort* bufA = xb + (size_t)NN * DIM;
    ushort* bufB = bufA + (size_t)NN * DIM;
    ushort* Wlb  = bufB + (size_t)NN * DIM;         // 12*128*128
    ushort* Wrb  = Wlb + (size_t)NL * DIM * DIM;
    ushort* W1b  = Wrb + (size_t)NL * DIM * DIM;    // 128*128

    const int* src = ei;
    const int* dst = ei + NE;

    int ncvt = NX8 + 2 * NW8 + NW18;
    cvt_all<<<(ncvt + 255) / 256, 256, 0, stream>>>(x, Wl, Wr, W1, xb, Wlb, Wrb, W1b);

    const int NB = (NN + 1023) / 1024;   // 49
    hipMemsetAsync(counts, 0, NN * sizeof(int), stream);
    count_kernel<<<(NE + 255) / 256, 256, 0, stream>>>(dst, counts);
    scan1_kernel<<<NB, 1024, 0, stream>>>(counts, offsets, bsums);
    scan2_kernel<<<1, 64, 0, stream>>>(bsums, bbase, NB);
    scan3_kernel<<<(NN + 1 + 255) / 256, 256, 0, stream>>>(offsets, bbase);
    hipMemsetAsync(counts, 0, NN * sizeof(int), stream);
    fill_kernel<<<(NE + 255) / 256, 256, 0, stream>>>(src, dst, offsets, counts, csr);

    static const int AGGRS[NL] = {0, 1, 2, 0, 1, 2, 0, 1, 2, 0, 2, 1};
    const ushort* h = xb;
    dim3 agrd((NN * 64 + 255) / 256);    // 12500 blocks: wave per node
    dim3 ggrd((NN + 63) / 64);           // 782 blocks
    ushort* aggbuf = bufB;               // dedicated aggregation scratch; h/out rotate xb<->bufA
    for (int i = 0; i < NL; ++i) {
        ushort* obuf = (h == xb) ? bufA : xb;
        if (AGGRS[i] == 0)
            aggregate_kernel<0><<<agrd, 256, 0, stream>>>(h, aggbuf, csr, offsets);
        else if (AGGRS[i] == 1)
            aggregate_kernel<1><<<agrd, 256, 0, stream>>>(h, aggbuf, csr, offsets);
        else
            aggregate_kernel<2><<<agrd, 256, 0, stream>>>(h, aggbuf, csr, offsets);
        gemm_kernel<2><<<ggrd, 256, 0, stream>>>(aggbuf, Wlb + (size_t)i * DIM * DIM, h,
                                                 Wrb + (size_t)i * DIM * DIM,
                                                 bl + (size_t)i * DIM, obuf);
        h = obuf;
    }
    // final MLP: relu(h@W1^T + b1) -> spare buffer, then 128->2 projection
    ushort* h2 = (h == xb) ? bufA : xb;
    gemm_kernel<1><<<ggrd, 256, 0, stream>>>(h, W1b, nullptr, nullptr, b1, h2);
    out_kernel<<<agrd, 256, 0, stream>>>(h2, W2, b2, out);
}